// Round 2
// baseline (378.149 us; speedup 1.0000x reference)
//
#include <hip/hip_runtime.h>
#include <math.h>

// Match numpy's non-FMA evaluation of the distance formula (ranking fidelity).
#pragma clang fp contract(off)

#define NPTS 4096
#define KNN  16
#define RPBK 16       // rows per block in knn kernel (one wave per row)
#define KT   1024     // knn threads per block
#define CAP  128      // filtered-candidate list capacity per row (knn phase 2)
#define CAPIN 64      // incoming-edge bucket capacity per row
#define SPILLCAP 262144

// ordered-uint transform: monotone map f32 -> u32 (canonicalize -0 -> +0 first)
__device__ __forceinline__ unsigned okey(float f) {
    f = f + 0.0f;
    unsigned u = __float_as_uint(f);
    return u ^ (((unsigned)((int)u >> 31)) | 0x80000000u);
}

__device__ __forceinline__ unsigned wmin32(unsigned v) {
    for (int o = 32; o > 0; o >>= 1) { unsigned w = __shfl_xor(v, o); v = w < v ? w : v; }
    return v;
}
__device__ __forceinline__ unsigned long long wmin64(unsigned long long v) {
    for (int o = 32; o > 0; o >>= 1) { unsigned long long w = __shfl_xor(v, o); v = w < v ? w : v; }
    return v;
}

// ---------------------------------------------------------------------------
__global__ void zero_kernel(float* __restrict__ p, int n) {
    int i = blockIdx.x * blockDim.x + threadIdx.x;
    if (i < n) p[i] = 0.0f;
}

// ---------------------------------------------------------------------------
// KNN via threshold-filter + exact small select. One wave per row.
// Selection key is lexicographic (okey(d2_formula), idx) == lax.top_k order.
// If do_inc != 0, winners additionally append themselves to the TARGET row's
// incoming bucket so row_kernel can compose output rows without global atomics.
// ---------------------------------------------------------------------------
__global__ __launch_bounds__(KT, 8) void knn_kernel(const float* __restrict__ xyz,
                                                    float* __restrict__ Dsum,
                                                    int* __restrict__ idx_out,
                                                    float* __restrict__ w_out,
                                                    int* __restrict__ cnt,
                                                    int* __restrict__ inc,
                                                    int* __restrict__ spillc,
                                                    int* __restrict__ spill,
                                                    int do_inc) {
    __shared__ float4 spts[NPTS];            // 64 KB: (x,y,z,|p|^2)
    __shared__ int    lists[RPBK][CAP];      // 8 KB

    const int t    = threadIdx.x;
    const int lane = t & 63;
    const int wv   = t >> 6;                              // local row
    const int rowg = blockIdx.x * RPBK + wv;              // 0..BN-1
    const int b    = rowg >> 12;
    const float* X = xyz + (size_t)b * 3 * NPTS;

    for (int i = t; i < NPTS; i += KT) {
        float x = X[i], y = X[NPTS + i], z = X[2 * NPTS + i];
        spts[i] = make_float4(x, y, z, (x * x + y * y) + z * z);   // numpy order
    }
    __syncthreads();

    const float4 P = spts[rowg & (NPTS - 1)];

    // ---- phase 1: per-lane chunk minimum; T = 16th smallest lane-min ----
    unsigned best1 = 0xFFFFFFFFu;
    for (int i = 0; i < NPTS / 64; ++i) {
        float4 Q  = spts[i * 64 + lane];
        float dot = (P.x * Q.x + P.y * Q.y) + P.z * Q.z;           // einsum order
        float d2  = (P.w + Q.w) - 2.0f * dot;                      // (sq+sq)-2dot
        unsigned k = okey(d2);
        best1 = k < best1 ? k : best1;
    }
    unsigned cur = best1, T = 0;
    for (int r = 0; r < KNN; ++r) {
        unsigned mn = wmin32(cur);
        T = mn;
        if (cur == mn) cur = 0xFFFFFFFFu;
    }

    // ---- phase 2: filter candidates with key <= T into LDS list ----
    int cnt2 = 0;
    for (int i = 0; i < NPTS / 64; ++i) {
        int m = i * 64 + lane;
        float4 Q  = spts[m];
        float dot = (P.x * Q.x + P.y * Q.y) + P.z * Q.z;
        float d2  = (P.w + Q.w) - 2.0f * dot;
        bool pass = okey(d2) <= T;
        unsigned long long bal = __ballot(pass);
        if (pass) {
            int pos = cnt2 + __popcll(bal & ((1ull << lane) - 1ull));
            if (pos < CAP) lists[wv][pos] = m;
        }
        cnt2 += (int)__popcll(bal);
    }

    // ---- phase 3: exact top-16 by (key, idx) ----
    unsigned long long sel = ~0ull;
    if (cnt2 <= CAP) {
        unsigned long long e0 = ~0ull, e1 = ~0ull;
        if (lane < cnt2) {
            int m = lists[wv][lane]; float4 Q = spts[m];
            float dot = (P.x * Q.x + P.y * Q.y) + P.z * Q.z;
            float d2  = (P.w + Q.w) - 2.0f * dot;
            e0 = ((unsigned long long)okey(d2) << 32) | (unsigned)m;
        }
        if (lane + 64 < cnt2) {
            int m = lists[wv][lane + 64]; float4 Q = spts[m];
            float dot = (P.x * Q.x + P.y * Q.y) + P.z * Q.z;
            float d2  = (P.w + Q.w) - 2.0f * dot;
            e1 = ((unsigned long long)okey(d2) << 32) | (unsigned)m;
        }
        unsigned long long c = e0 < e1 ? e0 : e1;
        for (int r = 0; r < KNN; ++r) {
            unsigned long long mn = wmin64(c);
            if (c == mn) {                       // unique key -> exactly one lane
                if (e0 == mn) e0 = ~0ull; else e1 = ~0ull;
                c = e0 < e1 ? e0 : e1;
            }
            if (lane == r) sel = mn;
        }
    } else {
        // overflow fallback (astronomically rare for random data): exact 16
        // rounds of strictly-increasing wave-min over the full candidate set
        unsigned long long last = 0;
        for (int r = 0; r < KNN; ++r) {
            unsigned long long bestp = ~0ull;
            for (int i = 0; i < NPTS / 64; ++i) {
                int m = i * 64 + lane;
                float4 Q  = spts[m];
                float dot = (P.x * Q.x + P.y * Q.y) + P.z * Q.z;
                float d2  = (P.w + Q.w) - 2.0f * dot;
                unsigned long long key = ((unsigned long long)okey(d2) << 32) | (unsigned)m;
                if (key > last && key < bestp) bestp = key;
            }
            unsigned long long mn = wmin64(bestp);
            if (lane == r) sel = mn;
            last = mn;
        }
    }

    // ---- winners on lanes 0..15: exact-diff weights, outputs, degrees,
    //      and (fused path) append to target row's incoming bucket ----
    float wgt = 0.0f;
    if (lane < KNN) {
        int j = (int)(unsigned)(sel & 0xFFFFFFFFull);
        float4 Q = spts[j];
        float dx = P.x - Q.x, dy = P.y - Q.y, dz = P.z - Q.z;
        float dist2 = (dx * dx + dy * dy) + dz * dz;                // numpy order
        wgt = expf(-(dist2 * 0.5f));                                // == -dist2/2.0
        size_t base = (size_t)rowg * KNN + lane;
        idx_out[base] = j;
        w_out[base]   = wgt;
        int jg = (b << 12) + j;
        atomicAdd(&Dsum[jg], 0.5f * wgt);                           // transpose half
        if (do_inc) {
            int pos = atomicAdd(&cnt[jg], 1);
            if (pos < CAPIN) {
                inc[(size_t)jg * CAPIN + pos] = (int)base;
            } else {
                int sp = atomicAdd(spillc, 1);
                if (sp < SPILLCAP) spill[sp] = (int)base;
            }
        }
    }
    float rs = wgt;
    for (int o = 32; o > 0; o >>= 1) rs += __shfl_xor(rs, o);
    if (lane == 0) atomicAdd(&Dsum[rowg], 0.5f * rs);               // outgoing half
}

// ---------------------------------------------------------------------------
__global__ void dis_kernel(const float* __restrict__ Dsum, float* __restrict__ dis, int n) {
    int i = blockIdx.x * blockDim.x + threadIdx.x;
    if (i < n) dis[i] = 1.0f / sqrtf(fmaxf(Dsum[i], 1e-6f));
}

// ---------------------------------------------------------------------------
// Fused fill+scatter: one block composes one full output row in LDS
// (zeros + outgoing entries + incoming entries + diagonal) and streams it
// out once with coalesced float4 stores. L is written exactly once; no
// global atomics on the 256 MB output.
// Value expression matches scatter_kernel bitwise:
//   v = -0.5f * w * dis[src] * dis[dst]   (left-to-right evaluation)
// ---------------------------------------------------------------------------
__global__ __launch_bounds__(256) void row_kernel(const int* __restrict__ idxb,
                                                  const float* __restrict__ wb,
                                                  const float* __restrict__ dis,
                                                  const int* __restrict__ cnt,
                                                  const int* __restrict__ inc,
                                                  float* __restrict__ L) {
    __shared__ float row[NPTS];                  // 16 KB
    const int r = blockIdx.x;                    // global row 0..BN-1
    const int b = r >> 12;
    const int n = r & (NPTS - 1);

    float4* row4 = (float4*)row;
    for (int i = threadIdx.x; i < NPTS / 4; i += 256)
        row4[i] = make_float4(0.0f, 0.0f, 0.0f, 0.0f);
    __syncthreads();

    const float dn = dis[r];

    // outgoing: 16 entries, unique columns (top-k indices unique)
    if (threadIdx.x < KNN) {
        int g = r * KNN + threadIdx.x;
        int j = idxb[g];
        float v = -0.5f * wb[g] * dn * dis[(b << 12) + j];
        atomicAdd(&row[j], v);
    }

    // incoming: bucket of source entries that selected this row
    int c = cnt[r];
    if (c > CAPIN) c = CAPIN;                    // overflow handled by spill_kernel
    for (int i = threadIdx.x; i < c; i += 256) {
        int g   = inc[(size_t)r * CAPIN + i];
        int src = g >> 4;                        // global source row
        float v = -0.5f * wb[g] * dis[src] * dn;
        atomicAdd(&row[src & (NPTS - 1)], v);
    }
    __syncthreads();

    // stream out, merging the unit diagonal on the fly
    float4* Lr = (float4*)(L + (size_t)b * NPTS * NPTS + (size_t)n * NPTS);
    const int dq = n >> 2, dl = n & 3;
    for (int i = threadIdx.x; i < NPTS / 4; i += 256) {
        float4 v = row4[i];
        if (i == dq) ((float*)&v)[dl] += 1.0f;
        Lr[i] = v;
    }
}

// ---------------------------------------------------------------------------
// Drain the (practically always empty) incoming-bucket overflow list.
// Runs after row_kernel, so plain global atomics are safe and complete.
// ---------------------------------------------------------------------------
__global__ __launch_bounds__(256) void spill_kernel(const int* __restrict__ spillc,
                                                    const int* __restrict__ spill,
                                                    const int* __restrict__ idxb,
                                                    const float* __restrict__ wb,
                                                    const float* __restrict__ dis,
                                                    float* __restrict__ L) {
    int c = spillc[0];
    if (c > SPILLCAP) c = SPILLCAP;
    for (int i = blockIdx.x * blockDim.x + threadIdx.x; i < c;
         i += gridDim.x * blockDim.x) {
        int g   = spill[i];
        int src = g >> 4;                        // global source row
        int b   = src >> 12;
        int nn  = src & (NPTS - 1);
        int j   = idxb[g];
        float v = -0.5f * wb[g] * dis[src] * dis[(b << 12) + j];
        // the missing placement is (j, nn) — row j got truncated incoming
        atomicAdd(L + (size_t)b * NPTS * NPTS + (size_t)j * NPTS + nn, v);
    }
}

// ---------------------------------------------------------------------------
// Fallback path (verified baseline): dense fill + global-atomic scatter.
// Used only if the workspace is too small for the incoming-bucket buffers.
// ---------------------------------------------------------------------------
__global__ __launch_bounds__(256) void fill_kernel(float4* __restrict__ L4, size_t T4) {
    size_t g4     = (size_t)blockIdx.x * blockDim.x + threadIdx.x;
    size_t stride = (size_t)gridDim.x * blockDim.x;
    for (; g4 < T4; g4 += stride) {
        size_t g = g4 << 2;
        int o    = (int)(g & (size_t)(NPTS * (size_t)NPTS - 1));   // N^2 = 2^24
        int row  = o >> 12;
        int col0 = o & (NPTS - 1);
        float4 v;
        v.x = (row == col0    ) ? 1.0f : 0.0f;
        v.y = (row == col0 + 1) ? 1.0f : 0.0f;
        v.z = (row == col0 + 2) ? 1.0f : 0.0f;
        v.w = (row == col0 + 3) ? 1.0f : 0.0f;
        L4[g4] = v;
    }
}

__global__ __launch_bounds__(256) void scatter_kernel(const int* __restrict__ idxb,
                                                      const float* __restrict__ wb,
                                                      const float* __restrict__ dis,
                                                      float* __restrict__ L) {
    int g   = blockIdx.x * 256 + threadIdx.x;     // 0..BN*K-1
    int row = g >> 4;
    int b   = row >> 12;
    int n   = row & (NPTS - 1);
    int j   = idxb[g];
    float v = -0.5f * wb[g] * dis[row] * dis[(b << 12) + j];
    float* Lb = L + (size_t)b * NPTS * NPTS;
    atomicAdd(Lb + (size_t)n * NPTS + j, v);
    atomicAdd(Lb + (size_t)j * NPTS + n, v);
}

// ---------------------------------------------------------------------------
extern "C" void kernel_launch(void* const* d_in, const int* in_sizes, int n_in,
                              void* d_out, int out_size, void* d_ws, size_t ws_size,
                              hipStream_t stream) {
    const float* xyz = (const float*)d_in[0];
    const int B  = in_sizes[0] / (3 * NPTS);            // 4
    const int BN = B * NPTS;                            // 16384

    // fused-path workspace layout (all 4-byte elems, ~7.3 MB total):
    // Dsum[BN] | cnt[BN] | spillc[16] | dis[BN] | idx[BN*K] | w[BN*K]
    //   | inc[BN*CAPIN] | spill[SPILLCAP]
    float* Dsum   = (float*)d_ws;
    int*   cnt    = (int*)(Dsum + BN);
    int*   spillc = cnt + BN;
    float* dis    = (float*)(spillc + 16);
    int*   idxb   = (int*)(dis + BN);
    float* wb     = (float*)(idxb + (size_t)BN * KNN);
    int*   inc    = (int*)(wb + (size_t)BN * KNN);
    int*   spill  = inc + (size_t)BN * CAPIN;
    float* L      = (float*)d_out;

    size_t need = ((size_t)BN * (3 + 2 * KNN + CAPIN) + 16 + SPILLCAP) * 4;
    const int fused = (ws_size >= need);

    if (fused) {
        int nz = 2 * BN + 16;                           // Dsum + cnt + spillc
        zero_kernel<<<(nz + 255) / 256, 256, 0, stream>>>(Dsum, nz);
        knn_kernel<<<BN / RPBK, KT, 0, stream>>>(xyz, Dsum, idxb, wb,
                                                 cnt, inc, spillc, spill, 1);
        dis_kernel<<<BN / 256, 256, 0, stream>>>(Dsum, dis, BN);
        row_kernel<<<BN, 256, 0, stream>>>(idxb, wb, dis, cnt, inc, L);
        spill_kernel<<<64, 256, 0, stream>>>(spillc, spill, idxb, wb, dis, L);
    } else {
        // verified-baseline fallback: fill + scatter (~2.25 MB workspace)
        float* fDsum = (float*)d_ws;
        float* fdis  = fDsum + BN;
        int*   fidx  = (int*)(fdis + BN);
        float* fwb   = (float*)(fidx + (size_t)BN * KNN);
        zero_kernel<<<BN / 256, 256, 0, stream>>>(fDsum, BN);
        knn_kernel<<<BN / RPBK, KT, 0, stream>>>(xyz, fDsum, fidx, fwb,
                                                 nullptr, nullptr, nullptr, nullptr, 0);
        dis_kernel<<<BN / 256, 256, 0, stream>>>(fDsum, fdis, BN);
        size_t T4 = (size_t)B * NPTS * NPTS / 4;
        fill_kernel<<<8192, 256, 0, stream>>>((float4*)d_out, T4);
        scatter_kernel<<<(BN * KNN) / 256, 256, 0, stream>>>(fidx, fwb, fdis, L);
    }
}

// Round 3
// 344.916 us; speedup vs baseline: 1.0963x; 1.0963x over previous
//
#include <hip/hip_runtime.h>
#include <math.h>

// Match numpy's non-FMA evaluation of the distance formula (ranking fidelity).
#pragma clang fp contract(off)

#define NPTS 4096
#define KNN  16
#define RPBK 32       // rows per block in knn kernel (16 waves x 2 rows/wave)
#define KT   1024     // knn threads per block
#define CAP  128      // filtered-candidate list capacity per row (knn phase 2)
#define CAPIN 64      // incoming-edge bucket capacity per row
#define SPILLCAP 262144
#define RROWS 2       // rows per block in row kernel

// ordered-uint transform: monotone map f32 -> u32 (canonicalize -0 -> +0 first)
// (used only in the rare knn fallback paths; hot paths compare floats directly)
__device__ __forceinline__ unsigned okey(float f) {
    f = f + 0.0f;
    unsigned u = __float_as_uint(f);
    return u ^ (((unsigned)((int)u >> 31)) | 0x80000000u);
}

__device__ __forceinline__ unsigned long long wmin64(unsigned long long v) {
    for (int o = 32; o > 0; o >>= 1) { unsigned long long w = __shfl_xor(v, o); v = w < v ? w : v; }
    return v;
}

// ---------------------------------------------------------------------------
__global__ void zero_kernel(float* __restrict__ p, int n) {
    int i = blockIdx.x * blockDim.x + threadIdx.x;
    if (i < n) p[i] = 0.0f;
}

// ---------------------------------------------------------------------------
// T = 16th smallest (by (value, lane)) of the 64 per-lane values.
// Rank via 64 independent broadcasts (latency-friendly, no dependent chain).
// Ranks are a permutation of 0..63, so exactly one lane has rank 15.
// ---------------------------------------------------------------------------
__device__ __forceinline__ float thresh16(float k, int lane) {
    int rank = 0;
    for (int s = 0; s < 64; ++s) {
        float ks = __shfl(k, s);
        rank += (ks < k || (ks == k && s < lane)) ? 1 : 0;
    }
    unsigned long long m = __ballot(rank == 15);
    return __shfl(k, __ffsll(m) - 1);
}

// ---------------------------------------------------------------------------
// Exact top-16 of the candidate list by (d2, idx); winner m lands on lane r
// for rank r. Fast path (cnt <= 64): rank + ds_permute (keys unique since
// list is ascending in idx => lane order == idx order; inf pads tie-broken
// by lane). Mid path (cnt <= CAP): verified 16-round u64 extraction.
// Slow path (cnt > CAP, astronomically rare): full rescan extraction.
// ---------------------------------------------------------------------------
__device__ __forceinline__ int select16(const float4* __restrict__ spts,
                                        const int* __restrict__ list,
                                        int cnt, float4 P, int lane) {
    if (cnt <= 64) {
        float key = __builtin_huge_valf();
        int m = -1;
        if (lane < cnt) {
            m = list[lane];
            float4 Q = spts[m];
            float dot = (P.x * Q.x + P.y * Q.y) + P.z * Q.z;
            key = (P.w + Q.w) - 2.0f * dot;
        }
        int rank = 0;
        for (int s = 0; s < 64; ++s) {
            float ks = __shfl(key, s);
            rank += (ks < key || (ks == key && s < lane)) ? 1 : 0;
        }
        // push m to lane 'rank'; lanes 0..15 receive the 16 smallest in order
        return __builtin_amdgcn_ds_permute(rank << 2, m);
    }
    if (cnt <= CAP) {
        unsigned long long e0 = ~0ull, e1 = ~0ull;
        if (lane < cnt) {
            int m = list[lane]; float4 Q = spts[m];
            float dot = (P.x * Q.x + P.y * Q.y) + P.z * Q.z;
            float d2  = (P.w + Q.w) - 2.0f * dot;
            e0 = ((unsigned long long)okey(d2) << 32) | (unsigned)m;
        }
        if (lane + 64 < cnt) {
            int m = list[lane + 64]; float4 Q = spts[m];
            float dot = (P.x * Q.x + P.y * Q.y) + P.z * Q.z;
            float d2  = (P.w + Q.w) - 2.0f * dot;
            e1 = ((unsigned long long)okey(d2) << 32) | (unsigned)m;
        }
        int selm = -1;
        unsigned long long c = e0 < e1 ? e0 : e1;
        for (int r = 0; r < KNN; ++r) {
            unsigned long long mn = wmin64(c);
            if (c == mn) {                       // unique key -> exactly one lane
                if (e0 == mn) e0 = ~0ull; else e1 = ~0ull;
                c = e0 < e1 ? e0 : e1;
            }
            if (lane == r) selm = (int)(unsigned)(mn & 0xFFFFFFFFull);
        }
        return selm;
    }
    // full fallback: exact 16 rounds of strictly-increasing wave-min
    unsigned long long last = 0; int selm = -1;
    for (int r = 0; r < KNN; ++r) {
        unsigned long long bestp = ~0ull;
        for (int i = 0; i < NPTS / 64; ++i) {
            int m = i * 64 + lane;
            float4 Q  = spts[m];
            float dot = (P.x * Q.x + P.y * Q.y) + P.z * Q.z;
            float d2  = (P.w + Q.w) - 2.0f * dot;
            unsigned long long key = ((unsigned long long)okey(d2) << 32) | (unsigned)m;
            if (key > last && key < bestp) bestp = key;
        }
        unsigned long long mn = wmin64(bestp);
        if (lane == r) selm = (int)(unsigned)(mn & 0xFFFFFFFFull);
        last = mn;
    }
    return selm;
}

// ---------------------------------------------------------------------------
// Winners on lanes 0..15: exact-diff weights, outputs, degree atomics, and
// (fused path) append to the target row's incoming bucket.
// ---------------------------------------------------------------------------
__device__ __forceinline__ void emit_row(int rowg, int b, int selm, float4 P,
                                         const float4* __restrict__ spts,
                                         float* __restrict__ Dsum,
                                         int* __restrict__ idx_out,
                                         float* __restrict__ w_out,
                                         int* __restrict__ cnt,
                                         int* __restrict__ inc,
                                         int* __restrict__ spillc,
                                         int* __restrict__ spill,
                                         int do_inc, int lane) {
    float wgt = 0.0f;
    if (lane < KNN) {
        int j = selm;
        float4 Q = spts[j];
        float dx = P.x - Q.x, dy = P.y - Q.y, dz = P.z - Q.z;
        float dist2 = (dx * dx + dy * dy) + dz * dz;                // numpy order
        wgt = expf(-(dist2 * 0.5f));                                // == -dist2/2.0
        size_t base = (size_t)rowg * KNN + lane;
        idx_out[base] = j;
        w_out[base]   = wgt;
        int jg = (b << 12) + j;
        atomicAdd(&Dsum[jg], 0.5f * wgt);                           // transpose half
        if (do_inc) {
            int pos = atomicAdd(&cnt[jg], 1);
            if (pos < CAPIN) {
                inc[(size_t)jg * CAPIN + pos] = (int)base;
            } else {
                int sp = atomicAdd(spillc, 1);
                if (sp < SPILLCAP) spill[sp] = (int)base;
            }
        }
    }
    float rs = wgt;
    for (int o = 32; o > 0; o >>= 1) rs += __shfl_xor(rs, o);
    if (lane == 0) atomicAdd(&Dsum[rowg], 0.5f * rs);               // outgoing half
}

// ---------------------------------------------------------------------------
// KNN via threshold-filter + exact small select. TWO rows per wave: each
// LDS point read feeds both rows' distance math (halves scan LDS traffic).
// Selection order is (d2, idx) lexicographic == lax.top_k order.
// ---------------------------------------------------------------------------
__global__ __launch_bounds__(KT, 8) void knn_kernel(const float* __restrict__ xyz,
                                                    float* __restrict__ Dsum,
                                                    int* __restrict__ idx_out,
                                                    float* __restrict__ w_out,
                                                    int* __restrict__ cnt,
                                                    int* __restrict__ inc,
                                                    int* __restrict__ spillc,
                                                    int* __restrict__ spill,
                                                    int do_inc) {
    __shared__ float4 spts[NPTS];            // 64 KB: (x,y,z,|p|^2)
    __shared__ int    lists[RPBK][CAP];      // 16 KB

    const int t    = threadIdx.x;
    const int lane = t & 63;
    const int wv   = t >> 6;                              // wave id 0..15
    const int row0 = blockIdx.x * RPBK + 2 * wv;          // this wave: row0, row0+1
    const int b    = row0 >> 12;
    const float* X = xyz + (size_t)b * 3 * NPTS;

    for (int i = t; i < NPTS; i += KT) {
        float x = X[i], y = X[NPTS + i], z = X[2 * NPTS + i];
        spts[i] = make_float4(x, y, z, (x * x + y * y) + z * z);   // numpy order
    }
    __syncthreads();

    const float4 PA = spts[row0 & (NPTS - 1)];
    const float4 PB = spts[(row0 + 1) & (NPTS - 1)];

    // ---- phase 1: per-lane chunk minima (both rows per point read) ----
    float bA = __builtin_huge_valf(), bB = __builtin_huge_valf();
    for (int i = 0; i < NPTS / 64; ++i) {
        float4 Q  = spts[i * 64 + lane];
        float dotA = (PA.x * Q.x + PA.y * Q.y) + PA.z * Q.z;       // einsum order
        float d2A  = (PA.w + Q.w) - 2.0f * dotA;                   // (sq+sq)-2dot
        float dotB = (PB.x * Q.x + PB.y * Q.y) + PB.z * Q.z;
        float d2B  = (PB.w + Q.w) - 2.0f * dotB;
        bA = fminf(bA, d2A);
        bB = fminf(bB, d2B);
    }
    const float TA = thresh16(bA, lane);     // >= 16th smallest d2 of row A
    const float TB = thresh16(bB, lane);

    // ---- phase 2: filter candidates with d2 <= T into LDS lists ----
    int* listA = &lists[2 * wv][0];
    int* listB = &lists[2 * wv + 1][0];
    int cA = 0, cB = 0;
    for (int i = 0; i < NPTS / 64; ++i) {
        int m = i * 64 + lane;
        float4 Q  = spts[m];
        float dotA = (PA.x * Q.x + PA.y * Q.y) + PA.z * Q.z;
        float d2A  = (PA.w + Q.w) - 2.0f * dotA;
        float dotB = (PB.x * Q.x + PB.y * Q.y) + PB.z * Q.z;
        float d2B  = (PB.w + Q.w) - 2.0f * dotB;
        bool pA = d2A <= TA;
        unsigned long long balA = __ballot(pA);
        if (pA) {
            int pos = cA + __popcll(balA & ((1ull << lane) - 1ull));
            if (pos < CAP) listA[pos] = m;
        }
        cA += (int)__popcll(balA);
        bool pB = d2B <= TB;
        unsigned long long balB = __ballot(pB);
        if (pB) {
            int pos = cB + __popcll(balB & ((1ull << lane) - 1ull));
            if (pos < CAP) listB[pos] = m;
        }
        cB += (int)__popcll(balB);
    }

    // ---- phase 3 + outputs, per row ----
    int selA = select16(spts, listA, cA, PA, lane);
    int selB = select16(spts, listB, cB, PB, lane);
    emit_row(row0,     b, selA, PA, spts, Dsum, idx_out, w_out,
             cnt, inc, spillc, spill, do_inc, lane);
    emit_row(row0 + 1, b, selB, PB, spts, Dsum, idx_out, w_out,
             cnt, inc, spillc, spill, do_inc, lane);
}

// ---------------------------------------------------------------------------
__global__ void dis_kernel(const float* __restrict__ Dsum, float* __restrict__ dis, int n) {
    int i = blockIdx.x * blockDim.x + threadIdx.x;
    if (i < n) dis[i] = 1.0f / sqrtf(fmaxf(Dsum[i], 1e-6f));
}

// ---------------------------------------------------------------------------
// Fused fill+scatter: one 512-thread block composes RROWS=2 consecutive
// output rows in LDS and streams them out once (32 KB contiguous float4).
// Value expression matches scatter_kernel bitwise:
//   v = -0.5f * w * dis[src] * dis[dst]   (left-to-right evaluation)
// ---------------------------------------------------------------------------
__global__ __launch_bounds__(512) void row_kernel(const int* __restrict__ idxb,
                                                  const float* __restrict__ wb,
                                                  const float* __restrict__ dis,
                                                  const int* __restrict__ cnt,
                                                  const int* __restrict__ inc,
                                                  float* __restrict__ L) {
    __shared__ float row[RROWS * NPTS];          // 32 KB
    const int r0 = blockIdx.x * RROWS;           // first global row
    const int b  = r0 >> 12;

    float4* row4 = (float4*)row;
    for (int i = threadIdx.x; i < RROWS * NPTS / 4; i += 512)
        row4[i] = make_float4(0.0f, 0.0f, 0.0f, 0.0f);
    __syncthreads();

    // sparse phase: 256 threads per row
    const int rr = threadIdx.x >> 8;             // 0..RROWS-1
    const int tt = threadIdx.x & 255;
    const int r  = r0 + rr;
    float* myrow = row + rr * NPTS;
    const float dn = dis[r];

    // outgoing: 16 entries, unique columns (top-k indices unique)
    if (tt < KNN) {
        int g = r * KNN + tt;
        int j = idxb[g];
        float v = -0.5f * wb[g] * dn * dis[(b << 12) + j];
        atomicAdd(&myrow[j], v);
    }

    // incoming: bucket of source entries that selected this row
    int c = cnt[r];
    if (c > CAPIN) c = CAPIN;                    // overflow handled by spill_kernel
    for (int i = tt; i < c; i += 256) {
        int g   = inc[(size_t)r * CAPIN + i];
        int src = g >> 4;                        // global source row
        float v = -0.5f * wb[g] * dis[src] * dn;
        atomicAdd(&myrow[src & (NPTS - 1)], v);
    }
    __syncthreads();

    // stream out (rows are consecutive in memory), merging the unit diagonal
    const int n0 = r0 & (NPTS - 1);
    float4* Lr = (float4*)(L + (size_t)b * NPTS * NPTS + (size_t)n0 * NPTS);
    for (int q = threadIdx.x; q < RROWS * NPTS / 4; q += 512) {
        float4 v = row4[q];
        int n = n0 + (q >> 10);                  // this float4's row (1024 f4/row)
        if ((q & 1023) == (n >> 2)) ((float*)&v)[n & 3] += 1.0f;
        Lr[q] = v;
    }
}

// ---------------------------------------------------------------------------
// Drain the (practically always empty) incoming-bucket overflow list.
// Runs after row_kernel, so plain global atomics are safe and complete.
// ---------------------------------------------------------------------------
__global__ __launch_bounds__(256) void spill_kernel(const int* __restrict__ spillc,
                                                    const int* __restrict__ spill,
                                                    const int* __restrict__ idxb,
                                                    const float* __restrict__ wb,
                                                    const float* __restrict__ dis,
                                                    float* __restrict__ L) {
    int c = spillc[0];
    if (c > SPILLCAP) c = SPILLCAP;
    for (int i = blockIdx.x * blockDim.x + threadIdx.x; i < c;
         i += gridDim.x * blockDim.x) {
        int g   = spill[i];
        int src = g >> 4;                        // global source row
        int b   = src >> 12;
        int nn  = src & (NPTS - 1);
        int j   = idxb[g];
        float v = -0.5f * wb[g] * dis[src] * dis[(b << 12) + j];
        // the missing placement is (j, nn) — row j got truncated incoming
        atomicAdd(L + (size_t)b * NPTS * NPTS + (size_t)j * NPTS + nn, v);
    }
}

// ---------------------------------------------------------------------------
// Fallback path (verified baseline): dense fill + global-atomic scatter.
// Used only if the workspace is too small for the incoming-bucket buffers.
// ---------------------------------------------------------------------------
__global__ __launch_bounds__(256) void fill_kernel(float4* __restrict__ L4, size_t T4) {
    size_t g4     = (size_t)blockIdx.x * blockDim.x + threadIdx.x;
    size_t stride = (size_t)gridDim.x * blockDim.x;
    for (; g4 < T4; g4 += stride) {
        size_t g = g4 << 2;
        int o    = (int)(g & (size_t)(NPTS * (size_t)NPTS - 1));   // N^2 = 2^24
        int row  = o >> 12;
        int col0 = o & (NPTS - 1);
        float4 v;
        v.x = (row == col0    ) ? 1.0f : 0.0f;
        v.y = (row == col0 + 1) ? 1.0f : 0.0f;
        v.z = (row == col0 + 2) ? 1.0f : 0.0f;
        v.w = (row == col0 + 3) ? 1.0f : 0.0f;
        L4[g4] = v;
    }
}

__global__ __launch_bounds__(256) void scatter_kernel(const int* __restrict__ idxb,
                                                      const float* __restrict__ wb,
                                                      const float* __restrict__ dis,
                                                      float* __restrict__ L) {
    int g   = blockIdx.x * 256 + threadIdx.x;     // 0..BN*K-1
    int row = g >> 4;
    int b   = row >> 12;
    int n   = row & (NPTS - 1);
    int j   = idxb[g];
    float v = -0.5f * wb[g] * dis[row] * dis[(b << 12) + j];
    float* Lb = L + (size_t)b * NPTS * NPTS;
    atomicAdd(Lb + (size_t)n * NPTS + j, v);
    atomicAdd(Lb + (size_t)j * NPTS + n, v);
}

// ---------------------------------------------------------------------------
extern "C" void kernel_launch(void* const* d_in, const int* in_sizes, int n_in,
                              void* d_out, int out_size, void* d_ws, size_t ws_size,
                              hipStream_t stream) {
    const float* xyz = (const float*)d_in[0];
    const int B  = in_sizes[0] / (3 * NPTS);            // 4
    const int BN = B * NPTS;                            // 16384

    // fused-path workspace layout (all 4-byte elems, ~7.3 MB total):
    // Dsum[BN] | cnt[BN] | spillc[16] | dis[BN] | idx[BN*K] | w[BN*K]
    //   | inc[BN*CAPIN] | spill[SPILLCAP]
    float* Dsum   = (float*)d_ws;
    int*   cnt    = (int*)(Dsum + BN);
    int*   spillc = cnt + BN;
    float* dis    = (float*)(spillc + 16);
    int*   idxb   = (int*)(dis + BN);
    float* wb     = (float*)(idxb + (size_t)BN * KNN);
    int*   inc    = (int*)(wb + (size_t)BN * KNN);
    int*   spill  = inc + (size_t)BN * CAPIN;
    float* L      = (float*)d_out;

    size_t need = ((size_t)BN * (3 + 2 * KNN + CAPIN) + 16 + SPILLCAP) * 4;
    const int fused = (ws_size >= need);

    if (fused) {
        int nz = 2 * BN + 16;                           // Dsum + cnt + spillc
        zero_kernel<<<(nz + 255) / 256, 256, 0, stream>>>(Dsum, nz);
        knn_kernel<<<BN / RPBK, KT, 0, stream>>>(xyz, Dsum, idxb, wb,
                                                 cnt, inc, spillc, spill, 1);
        dis_kernel<<<BN / 256, 256, 0, stream>>>(Dsum, dis, BN);
        row_kernel<<<BN / RROWS, 512, 0, stream>>>(idxb, wb, dis, cnt, inc, L);
        spill_kernel<<<64, 256, 0, stream>>>(spillc, spill, idxb, wb, dis, L);
    } else {
        // verified-baseline fallback: fill + scatter (~2.25 MB workspace)
        float* fDsum = (float*)d_ws;
        float* fdis  = fDsum + BN;
        int*   fidx  = (int*)(fdis + BN);
        float* fwb   = (float*)(fidx + (size_t)BN * KNN);
        zero_kernel<<<BN / 256, 256, 0, stream>>>(fDsum, BN);
        knn_kernel<<<BN / RPBK, KT, 0, stream>>>(xyz, fDsum, fidx, fwb,
                                                 nullptr, nullptr, nullptr, nullptr, 0);
        dis_kernel<<<BN / 256, 256, 0, stream>>>(fDsum, fdis, BN);
        size_t T4 = (size_t)B * NPTS * NPTS / 4;
        fill_kernel<<<8192, 256, 0, stream>>>((float4*)d_out, T4);
        scatter_kernel<<<(BN * KNN) / 256, 256, 0, stream>>>(fidx, fwb, fdis, L);
    }
}

// Round 4
// 340.215 us; speedup vs baseline: 1.1115x; 1.0138x over previous
//
#include <hip/hip_runtime.h>
#include <math.h>

// Match numpy's non-FMA evaluation of the distance formula (ranking fidelity).
#pragma clang fp contract(off)

#define NPTS 4096
#define KNN  16
#define RPBK 32       // rows per block in knn kernel (16 waves x 2 rows/wave)
#define KT   1024     // knn threads per block
#define CAP  128      // filtered-candidate list capacity per row (knn phase 2)
#define CAPIN 64      // incoming-edge bucket capacity per row
#define SPILLCAP 262144
#define RROWS 4       // rows per block in row kernel (1024 threads)

// ordered-uint transform: monotone map f32 -> u32 (canonicalize -0 -> +0 first)
// (used only in the rare knn fallback paths; hot paths compare floats directly)
__device__ __forceinline__ unsigned okey(float f) {
    f = f + 0.0f;
    unsigned u = __float_as_uint(f);
    return u ^ (((unsigned)((int)u >> 31)) | 0x80000000u);
}

__device__ __forceinline__ unsigned long long wmin64(unsigned long long v) {
    for (int o = 32; o > 0; o >>= 1) { unsigned long long w = __shfl_xor(v, o); v = w < v ? w : v; }
    return v;
}

// ---------------------------------------------------------------------------
__global__ void zero_kernel(float* __restrict__ p, int n) {
    int i = blockIdx.x * blockDim.x + threadIdx.x;
    if (i < n) p[i] = 0.0f;
}

// ---------------------------------------------------------------------------
// T = 16th smallest (by (value, lane)) of the 64 per-lane values.
// Rank via 64 independent broadcasts (latency-friendly, no dependent chain).
// Ranks are a permutation of 0..63, so exactly one lane has rank 15.
// ---------------------------------------------------------------------------
__device__ __forceinline__ float thresh16(float k, int lane) {
    int rank = 0;
    for (int s = 0; s < 64; ++s) {
        float ks = __shfl(k, s);
        rank += (ks < k || (ks == k && s < lane)) ? 1 : 0;
    }
    unsigned long long m = __ballot(rank == 15);
    return __shfl(k, __ffsll(m) - 1);
}

// ---------------------------------------------------------------------------
// Exact top-16 of the candidate list by (d2, idx); winner m lands on lane r
// for rank r. Fast path (cnt <= 64): rank + ds_permute (keys unique since
// list is ascending in idx => lane order == idx order; inf pads tie-broken
// by lane). Mid path (cnt <= CAP): verified 16-round u64 extraction.
// Slow path (cnt > CAP, astronomically rare): full rescan extraction.
// ---------------------------------------------------------------------------
__device__ __forceinline__ int select16(const float4* __restrict__ spts,
                                        const int* __restrict__ list,
                                        int cnt, float4 P, int lane) {
    if (cnt <= 64) {
        float key = __builtin_huge_valf();
        int m = -1;
        if (lane < cnt) {
            m = list[lane];
            float4 Q = spts[m];
            float dot = (P.x * Q.x + P.y * Q.y) + P.z * Q.z;
            key = (P.w + Q.w) - 2.0f * dot;
        }
        int rank = 0;
        for (int s = 0; s < 64; ++s) {
            float ks = __shfl(key, s);
            rank += (ks < key || (ks == key && s < lane)) ? 1 : 0;
        }
        // push m to lane 'rank'; lanes 0..15 receive the 16 smallest in order
        return __builtin_amdgcn_ds_permute(rank << 2, m);
    }
    if (cnt <= CAP) {
        unsigned long long e0 = ~0ull, e1 = ~0ull;
        if (lane < cnt) {
            int m = list[lane]; float4 Q = spts[m];
            float dot = (P.x * Q.x + P.y * Q.y) + P.z * Q.z;
            float d2  = (P.w + Q.w) - 2.0f * dot;
            e0 = ((unsigned long long)okey(d2) << 32) | (unsigned)m;
        }
        if (lane + 64 < cnt) {
            int m = list[lane + 64]; float4 Q = spts[m];
            float dot = (P.x * Q.x + P.y * Q.y) + P.z * Q.z;
            float d2  = (P.w + Q.w) - 2.0f * dot;
            e1 = ((unsigned long long)okey(d2) << 32) | (unsigned)m;
        }
        int selm = -1;
        unsigned long long c = e0 < e1 ? e0 : e1;
        for (int r = 0; r < KNN; ++r) {
            unsigned long long mn = wmin64(c);
            if (c == mn) {                       // unique key -> exactly one lane
                if (e0 == mn) e0 = ~0ull; else e1 = ~0ull;
                c = e0 < e1 ? e0 : e1;
            }
            if (lane == r) selm = (int)(unsigned)(mn & 0xFFFFFFFFull);
        }
        return selm;
    }
    // full fallback: exact 16 rounds of strictly-increasing wave-min
    unsigned long long last = 0; int selm = -1;
    for (int r = 0; r < KNN; ++r) {
        unsigned long long bestp = ~0ull;
        for (int i = 0; i < NPTS / 64; ++i) {
            int m = i * 64 + lane;
            float4 Q  = spts[m];
            float dot = (P.x * Q.x + P.y * Q.y) + P.z * Q.z;
            float d2  = (P.w + Q.w) - 2.0f * dot;
            unsigned long long key = ((unsigned long long)okey(d2) << 32) | (unsigned)m;
            if (key > last && key < bestp) bestp = key;
        }
        unsigned long long mn = wmin64(bestp);
        if (lane == r) selm = (int)(unsigned)(mn & 0xFFFFFFFFull);
        last = mn;
    }
    return selm;
}

// ---------------------------------------------------------------------------
// Winners on lanes 0..15: exact-diff weights, outputs, degree atomics, and
// (fused path) append to the target row's incoming bucket.
// ---------------------------------------------------------------------------
__device__ __forceinline__ void emit_row(int rowg, int b, int selm, float4 P,
                                         const float4* __restrict__ spts,
                                         float* __restrict__ Dsum,
                                         int* __restrict__ idx_out,
                                         float* __restrict__ w_out,
                                         int* __restrict__ cnt,
                                         int* __restrict__ inc,
                                         int* __restrict__ spillc,
                                         int* __restrict__ spill,
                                         int do_inc, int lane) {
    float wgt = 0.0f;
    if (lane < KNN) {
        int j = selm;
        float4 Q = spts[j];
        float dx = P.x - Q.x, dy = P.y - Q.y, dz = P.z - Q.z;
        float dist2 = (dx * dx + dy * dy) + dz * dz;                // numpy order
        wgt = expf(-(dist2 * 0.5f));                                // == -dist2/2.0
        size_t base = (size_t)rowg * KNN + lane;
        idx_out[base] = j;
        w_out[base]   = wgt;
        int jg = (b << 12) + j;
        atomicAdd(&Dsum[jg], 0.5f * wgt);                           // transpose half
        if (do_inc) {
            int pos = atomicAdd(&cnt[jg], 1);
            if (pos < CAPIN) {
                inc[(size_t)jg * CAPIN + pos] = (int)base;
            } else {
                int sp = atomicAdd(spillc, 1);
                if (sp < SPILLCAP) spill[sp] = (int)base;
            }
        }
    }
    float rs = wgt;
    for (int o = 32; o > 0; o >>= 1) rs += __shfl_xor(rs, o);
    if (lane == 0) atomicAdd(&Dsum[rowg], 0.5f * rs);               // outgoing half
}

// ---------------------------------------------------------------------------
// KNN via threshold-filter + exact small select. TWO rows per wave: each
// LDS point read feeds both rows' distance math (halves scan LDS traffic).
// Selection order is (d2, idx) lexicographic == lax.top_k order.
// NOTE launch_bounds min-waves/EU = 4 (not 8): 8 caps VGPRs at 64 and forces
// scratch spills for this register-heavy 2-row pipeline; LDS (80 KB) limits
// us to 2 blocks/CU regardless, so the 8-waves request bought nothing.
// ---------------------------------------------------------------------------
__global__ __launch_bounds__(KT, 4) void knn_kernel(const float* __restrict__ xyz,
                                                    float* __restrict__ Dsum,
                                                    int* __restrict__ idx_out,
                                                    float* __restrict__ w_out,
                                                    int* __restrict__ cnt,
                                                    int* __restrict__ inc,
                                                    int* __restrict__ spillc,
                                                    int* __restrict__ spill,
                                                    int do_inc) {
    __shared__ float4 spts[NPTS];            // 64 KB: (x,y,z,|p|^2)
    __shared__ int    lists[RPBK][CAP];      // 16 KB

    const int t    = threadIdx.x;
    const int lane = t & 63;
    const int wv   = t >> 6;                              // wave id 0..15
    const int row0 = blockIdx.x * RPBK + 2 * wv;          // this wave: row0, row0+1
    const int b    = row0 >> 12;
    const float* X = xyz + (size_t)b * 3 * NPTS;

    for (int i = t; i < NPTS; i += KT) {
        float x = X[i], y = X[NPTS + i], z = X[2 * NPTS + i];
        spts[i] = make_float4(x, y, z, (x * x + y * y) + z * z);   // numpy order
    }
    __syncthreads();

    const float4 PA = spts[row0 & (NPTS - 1)];
    const float4 PB = spts[(row0 + 1) & (NPTS - 1)];

    // ---- phase 1: per-lane chunk minima (both rows per point read) ----
    float bA = __builtin_huge_valf(), bB = __builtin_huge_valf();
    for (int i = 0; i < NPTS / 64; ++i) {
        float4 Q  = spts[i * 64 + lane];
        float dotA = (PA.x * Q.x + PA.y * Q.y) + PA.z * Q.z;       // einsum order
        float d2A  = (PA.w + Q.w) - 2.0f * dotA;                   // (sq+sq)-2dot
        float dotB = (PB.x * Q.x + PB.y * Q.y) + PB.z * Q.z;
        float d2B  = (PB.w + Q.w) - 2.0f * dotB;
        bA = fminf(bA, d2A);
        bB = fminf(bB, d2B);
    }
    const float TA = thresh16(bA, lane);     // >= 16th smallest d2 of row A
    const float TB = thresh16(bB, lane);

    // ---- phase 2: filter candidates with d2 <= T into LDS lists ----
    int* listA = &lists[2 * wv][0];
    int* listB = &lists[2 * wv + 1][0];
    int cA = 0, cB = 0;
    for (int i = 0; i < NPTS / 64; ++i) {
        int m = i * 64 + lane;
        float4 Q  = spts[m];
        float dotA = (PA.x * Q.x + PA.y * Q.y) + PA.z * Q.z;
        float d2A  = (PA.w + Q.w) - 2.0f * dotA;
        float dotB = (PB.x * Q.x + PB.y * Q.y) + PB.z * Q.z;
        float d2B  = (PB.w + Q.w) - 2.0f * dotB;
        bool pA = d2A <= TA;
        unsigned long long balA = __ballot(pA);
        if (pA) {
            int pos = cA + __popcll(balA & ((1ull << lane) - 1ull));
            if (pos < CAP) listA[pos] = m;
        }
        cA += (int)__popcll(balA);
        bool pB = d2B <= TB;
        unsigned long long balB = __ballot(pB);
        if (pB) {
            int pos = cB + __popcll(balB & ((1ull << lane) - 1ull));
            if (pos < CAP) listB[pos] = m;
        }
        cB += (int)__popcll(balB);
    }

    // ---- phase 3 + outputs, per row ----
    int selA = select16(spts, listA, cA, PA, lane);
    int selB = select16(spts, listB, cB, PB, lane);
    emit_row(row0,     b, selA, PA, spts, Dsum, idx_out, w_out,
             cnt, inc, spillc, spill, do_inc, lane);
    emit_row(row0 + 1, b, selB, PB, spts, Dsum, idx_out, w_out,
             cnt, inc, spillc, spill, do_inc, lane);
}

// ---------------------------------------------------------------------------
__global__ void dis_kernel(const float* __restrict__ Dsum, float* __restrict__ dis, int n) {
    int i = blockIdx.x * blockDim.x + threadIdx.x;
    if (i < n) dis[i] = 1.0f / sqrtf(fmaxf(Dsum[i], 1e-6f));
}

// ---------------------------------------------------------------------------
// Fused fill+scatter: one 1024-thread block composes RROWS=4 consecutive
// output rows in LDS and streams them out once (64 KB contiguous float4).
// Value expression matches scatter_kernel bitwise:
//   v = -0.5f * w * dis[src] * dis[dst]   (left-to-right evaluation)
// ---------------------------------------------------------------------------
__global__ __launch_bounds__(1024, 4) void row_kernel(const int* __restrict__ idxb,
                                                      const float* __restrict__ wb,
                                                      const float* __restrict__ dis,
                                                      const int* __restrict__ cnt,
                                                      const int* __restrict__ inc,
                                                      float* __restrict__ L) {
    __shared__ float row[RROWS * NPTS];          // 64 KB
    const int r0 = blockIdx.x * RROWS;           // first global row
    const int b  = r0 >> 12;

    float4* row4 = (float4*)row;
    for (int i = threadIdx.x; i < RROWS * NPTS / 4; i += 1024)
        row4[i] = make_float4(0.0f, 0.0f, 0.0f, 0.0f);
    __syncthreads();

    // sparse phase: 256 threads per row
    const int rr = threadIdx.x >> 8;             // 0..RROWS-1
    const int tt = threadIdx.x & 255;
    const int r  = r0 + rr;
    float* myrow = row + rr * NPTS;
    const float dn = dis[r];

    // outgoing: 16 entries, unique columns (top-k indices unique)
    if (tt < KNN) {
        int g = r * KNN + tt;
        int j = idxb[g];
        float v = -0.5f * wb[g] * dn * dis[(b << 12) + j];
        atomicAdd(&myrow[j], v);
    }

    // incoming: bucket of source entries that selected this row
    int c = cnt[r];
    if (c > CAPIN) c = CAPIN;                    // overflow handled by spill_kernel
    for (int i = tt; i < c; i += 256) {
        int g   = inc[(size_t)r * CAPIN + i];
        int src = g >> 4;                        // global source row
        float v = -0.5f * wb[g] * dis[src] * dn;
        atomicAdd(&myrow[src & (NPTS - 1)], v);
    }
    __syncthreads();

    // stream out (rows are consecutive in memory), merging the unit diagonal
    const int n0 = r0 & (NPTS - 1);
    float4* Lr = (float4*)(L + (size_t)b * NPTS * NPTS + (size_t)n0 * NPTS);
    for (int q = threadIdx.x; q < RROWS * NPTS / 4; q += 1024) {
        float4 v = row4[q];
        int n = n0 + (q >> 10);                  // this float4's row (1024 f4/row)
        if ((q & 1023) == (n >> 2)) ((float*)&v)[n & 3] += 1.0f;
        Lr[q] = v;
    }
}

// ---------------------------------------------------------------------------
// Drain the (practically always empty) incoming-bucket overflow list.
// Runs after row_kernel, so plain global atomics are safe and complete.
// ---------------------------------------------------------------------------
__global__ __launch_bounds__(256) void spill_kernel(const int* __restrict__ spillc,
                                                    const int* __restrict__ spill,
                                                    const int* __restrict__ idxb,
                                                    const float* __restrict__ wb,
                                                    const float* __restrict__ dis,
                                                    float* __restrict__ L) {
    int c = spillc[0];
    if (c > SPILLCAP) c = SPILLCAP;
    for (int i = blockIdx.x * blockDim.x + threadIdx.x; i < c;
         i += gridDim.x * blockDim.x) {
        int g   = spill[i];
        int src = g >> 4;                        // global source row
        int b   = src >> 12;
        int nn  = src & (NPTS - 1);
        int j   = idxb[g];
        float v = -0.5f * wb[g] * dis[src] * dis[(b << 12) + j];
        // the missing placement is (j, nn) — row j got truncated incoming
        atomicAdd(L + (size_t)b * NPTS * NPTS + (size_t)j * NPTS + nn, v);
    }
}

// ---------------------------------------------------------------------------
// Fallback path (verified baseline): dense fill + global-atomic scatter.
// Used only if the workspace is too small for the incoming-bucket buffers.
// ---------------------------------------------------------------------------
__global__ __launch_bounds__(256) void fill_kernel(float4* __restrict__ L4, size_t T4) {
    size_t g4     = (size_t)blockIdx.x * blockDim.x + threadIdx.x;
    size_t stride = (size_t)gridDim.x * blockDim.x;
    for (; g4 < T4; g4 += stride) {
        size_t g = g4 << 2;
        int o    = (int)(g & (size_t)(NPTS * (size_t)NPTS - 1));   // N^2 = 2^24
        int row  = o >> 12;
        int col0 = o & (NPTS - 1);
        float4 v;
        v.x = (row == col0    ) ? 1.0f : 0.0f;
        v.y = (row == col0 + 1) ? 1.0f : 0.0f;
        v.z = (row == col0 + 2) ? 1.0f : 0.0f;
        v.w = (row == col0 + 3) ? 1.0f : 0.0f;
        L4[g4] = v;
    }
}

__global__ __launch_bounds__(256) void scatter_kernel(const int* __restrict__ idxb,
                                                      const float* __restrict__ wb,
                                                      const float* __restrict__ dis,
                                                      float* __restrict__ L) {
    int g   = blockIdx.x * 256 + threadIdx.x;     // 0..BN*K-1
    int row = g >> 4;
    int b   = row >> 12;
    int n   = row & (NPTS - 1);
    int j   = idxb[g];
    float v = -0.5f * wb[g] * dis[row] * dis[(b << 12) + j];
    float* Lb = L + (size_t)b * NPTS * NPTS;
    atomicAdd(Lb + (size_t)n * NPTS + j, v);
    atomicAdd(Lb + (size_t)j * NPTS + n, v);
}

// ---------------------------------------------------------------------------
extern "C" void kernel_launch(void* const* d_in, const int* in_sizes, int n_in,
                              void* d_out, int out_size, void* d_ws, size_t ws_size,
                              hipStream_t stream) {
    const float* xyz = (const float*)d_in[0];
    const int B  = in_sizes[0] / (3 * NPTS);            // 4
    const int BN = B * NPTS;                            // 16384

    // fused-path workspace layout (all 4-byte elems, ~7.3 MB total):
    // Dsum[BN] | cnt[BN] | spillc[16] | dis[BN] | idx[BN*K] | w[BN*K]
    //   | inc[BN*CAPIN] | spill[SPILLCAP]
    float* Dsum   = (float*)d_ws;
    int*   cnt    = (int*)(Dsum + BN);
    int*   spillc = cnt + BN;
    float* dis    = (float*)(spillc + 16);
    int*   idxb   = (int*)(dis + BN);
    float* wb     = (float*)(idxb + (size_t)BN * KNN);
    int*   inc    = (int*)(wb + (size_t)BN * KNN);
    int*   spill  = inc + (size_t)BN * CAPIN;
    float* L      = (float*)d_out;

    size_t need = ((size_t)BN * (3 + 2 * KNN + CAPIN) + 16 + SPILLCAP) * 4;
    const int fused = (ws_size >= need);

    if (fused) {
        int nz = 2 * BN + 16;                           // Dsum + cnt + spillc
        zero_kernel<<<(nz + 255) / 256, 256, 0, stream>>>(Dsum, nz);
        knn_kernel<<<BN / RPBK, KT, 0, stream>>>(xyz, Dsum, idxb, wb,
                                                 cnt, inc, spillc, spill, 1);
        dis_kernel<<<BN / 256, 256, 0, stream>>>(Dsum, dis, BN);
        row_kernel<<<BN / RROWS, 1024, 0, stream>>>(idxb, wb, dis, cnt, inc, L);
        spill_kernel<<<64, 256, 0, stream>>>(spillc, spill, idxb, wb, dis, L);
    } else {
        // verified-baseline fallback: fill + scatter (~2.25 MB workspace)
        float* fDsum = (float*)d_ws;
        float* fdis  = fDsum + BN;
        int*   fidx  = (int*)(fdis + BN);
        float* fwb   = (float*)(fidx + (size_t)BN * KNN);
        zero_kernel<<<BN / 256, 256, 0, stream>>>(fDsum, BN);
        knn_kernel<<<BN / RPBK, KT, 0, stream>>>(xyz, fDsum, fidx, fwb,
                                                 nullptr, nullptr, nullptr, nullptr, 0);
        dis_kernel<<<BN / 256, 256, 0, stream>>>(fDsum, fdis, BN);
        size_t T4 = (size_t)B * NPTS * NPTS / 4;
        fill_kernel<<<8192, 256, 0, stream>>>((float4*)d_out, T4);
        scatter_kernel<<<(BN * KNN) / 256, 256, 0, stream>>>(fidx, fwb, fdis, L);
    }
}